// Round 10
// baseline (277.814 us; speedup 1.0000x reference)
//
#include <hip/hip_runtime.h>

#define P_CNT 32768
#define D_DIM 256
#define B_SZ  256
#define INVT  20.0f          // 1/TEMP
#define NEG_BIG -3.0e38f
#define SLICE_N 4096
#define NSLICE 8
#define CAP 128

typedef _Float16 half8  __attribute__((ext_vector_type(8)));
typedef _Float16 half4v __attribute__((ext_vector_type(4)));
typedef float    floatx4 __attribute__((ext_vector_type(4)));

// ---------------- 4-wave (256-thread) block reductions ----------------
__device__ __forceinline__ float blockMax4(float v, int tid, float* red4) {
#pragma unroll
  for (int off = 1; off < 64; off <<= 1) v = fmaxf(v, __shfl_xor(v, off));
  if ((tid & 63) == 0) red4[tid >> 6] = v;
  __syncthreads();
  float r = fmaxf(fmaxf(red4[0], red4[1]), fmaxf(red4[2], red4[3]));
  __syncthreads();
  return r;
}

__device__ __forceinline__ float blockSum4(float v, int tid, float* red4) {
#pragma unroll
  for (int off = 1; off < 64; off <<= 1) v += __shfl_xor(v, off);
  if ((tid & 63) == 0) red4[tid >> 6] = v;
  __syncthreads();
  float r = red4[0] + red4[1] + red4[2] + red4[3];
  __syncthreads();
  return r;
}

// ---------------- per-slice candidate superset collect ----------------
// Collects ALL elements in the smallest tail bin-range whose count >= K
// (a superset of the slice's top-K). 256 EW bins over [hi-range, hi],
// bin 0 = bulk (never counted, never collected). Exact ranking happens in P2.
template <typename GetV, typename GetI>
__device__ void selectCollect(GetV getv, GetI geti, int K, float hi, float range0,
                              int tid, int lane,
                              int* hist, int* ibc, int* lcnt,
                              float* oVal, int* oIdx, int* oCnt) {
  float range = range0;
  for (int guard = 0; guard < 10; ++guard) {
    const float lo = hi - range;
    const float scale = 256.0f / range;
    hist[tid] = 0;
    if (tid == 0) ibc[0] = -1;
    __syncthreads();
#pragma unroll
    for (int j = 0; j < 16; ++j) {
      float v = getv(j);
      float t = (v - lo) * scale;
      int bin = (int)fminf(fmaxf(t, 0.0f), 255.0f);
      if (bin >= 1) atomicAdd(&hist[bin], 1);
    }
    __syncthreads();
    if (tid < 64) {
      int4 h = ((const int4*)hist)[tid];
      if (tid == 0) h.x = 0;                       // exclude bulk bin 0
      int L = h.x + h.y + h.z + h.w;
      int S = L;
#pragma unroll
      for (int off = 1; off < 64; off <<= 1) {
        int y = __shfl_down(S, off);
        S += (lane + off < 64) ? y : 0;
      }
      int total = __shfl(S, 0);
      if (total >= K) {
        int above = S - L;                          // count in bins > 4*tid+3
        if (above < K && S >= K) {                  // unique boundary lane
          int a = above, bsel;
          if (a + h.w >= K) bsel = 4 * tid + 3;
          else { a += h.w;
            if (a + h.z >= K) bsel = 4 * tid + 2;
            else { a += h.z;
              if (a + h.y >= K) bsel = 4 * tid + 1;
              else bsel = 4 * tid;                  // S>=K guarantees this
            } }
          ibc[0] = bsel;
        }
      }
    }
    __syncthreads();
    if (ibc[0] >= 0) {
      const int Bstar = ibc[0];
      if (tid == 0) *lcnt = 0;
      __syncthreads();
#pragma unroll
      for (int j = 0; j < 16; ++j) {
        float v = getv(j);
        float t = (v - lo) * scale;
        int bin = (int)fminf(fmaxf(t, 0.0f), 255.0f);
        if (bin >= Bstar) {
          int tt = atomicAdd(lcnt, 1);
          if (tt < CAP) { oVal[tt] = v; oIdx[tt] = geti(j); }
        }
      }
      __syncthreads();
      if (tid == 0) *oCnt = min(*lcnt, CAP);
      return;
    }
    range *= 4.0f;                                  // tail too sparse: extend
    __syncthreads();
  }
  if (tid == 0) *oCnt = 0;                          // unreachable for real data
}

// ---------------- kernel 0: gather prx, build A' = [features; mem[prx]] ----------------
__global__ void prep_kernel(const float* __restrict__ features,
                            const int* __restrict__ targets,
                            const int* __restrict__ all_prx,
                            const float* __restrict__ mem,
                            float* __restrict__ A2,
                            int* __restrict__ prxArr) {
  const int b = blockIdx.x;
  const int k = threadIdx.x;
  const int t = targets[b];
  const int pr = all_prx[t];
  if (k == 0) prxArr[b] = pr;
  A2[b * D_DIM + k] = features[b * D_DIM + k];
  A2[(B_SZ + b) * D_DIM + k] = mem[(size_t)pr * D_DIM + k];
}

// ---------------- kernel 1: split-fp16 3-pass MFMA GEMM ----------------
__global__ __launch_bounds__(256) void gemm_mfma(const float* __restrict__ A,
                                                 const float* __restrict__ Bm,
                                                 float* __restrict__ Co) {
  __shared__ _Float16 Ah[128][32], Al[128][32], Bh[128][32], Bl[128][32];
  const int tid = threadIdx.x;
  const int lane = tid & 63;
  const int wid = tid >> 6;
  const int wr = wid >> 1, wc = wid & 1;
  const int orig = (blockIdx.x & 7) * 128 + (blockIdx.x >> 3);
  const int rowBase = (orig & 3) << 7;
  const int colBase = (orig >> 2) << 7;

  const int trow = tid >> 3;
  const int tseg = tid & 7;

  floatx4 acc[4][4];
#pragma unroll
  for (int i = 0; i < 4; ++i)
#pragma unroll
    for (int j = 0; j < 4; ++j) {
      acc[i][j][0] = 0.f; acc[i][j][1] = 0.f; acc[i][j][2] = 0.f; acc[i][j][3] = 0.f;
    }

  const int fr = lane & 15;
  const int kg = (lane >> 4) << 3;

  for (int step = 0; step < 8; ++step) {
    const int k0 = step << 5;
    float4 sa[4], sb[4];
#pragma unroll
    for (int p = 0; p < 4; ++p) {
      const int r = trow + (p << 5);
      sa[p] = *(const float4*)(A  + (size_t)(rowBase + r) * D_DIM + k0 + tseg * 4);
      sb[p] = *(const float4*)(Bm + (size_t)(colBase + r) * D_DIM + k0 + tseg * 4);
    }
    __syncthreads();
#pragma unroll
    for (int p = 0; p < 4; ++p) {
      const int r = trow + (p << 5);
      float4 v = sa[p];
      half4v h, l;
      h[0] = (_Float16)v.x; l[0] = (_Float16)(v.x - (float)h[0]);
      h[1] = (_Float16)v.y; l[1] = (_Float16)(v.y - (float)h[1]);
      h[2] = (_Float16)v.z; l[2] = (_Float16)(v.z - (float)h[2]);
      h[3] = (_Float16)v.w; l[3] = (_Float16)(v.w - (float)h[3]);
      *(half4v*)&Ah[r][tseg * 4] = h;
      *(half4v*)&Al[r][tseg * 4] = l;
      v = sb[p];
      h[0] = (_Float16)v.x; l[0] = (_Float16)(v.x - (float)h[0]);
      h[1] = (_Float16)v.y; l[1] = (_Float16)(v.y - (float)h[1]);
      h[2] = (_Float16)v.z; l[2] = (_Float16)(v.z - (float)h[2]);
      h[3] = (_Float16)v.w; l[3] = (_Float16)(v.w - (float)h[3]);
      *(half4v*)&Bh[r][tseg * 4] = h;
      *(half4v*)&Bl[r][tseg * 4] = l;
    }
    __syncthreads();
    half8 ah[4], al[4], bh[4], bl[4];
#pragma unroll
    for (int f = 0; f < 4; ++f) {
      ah[f] = *(const half8*)&Ah[wr * 64 + f * 16 + fr][kg];
      al[f] = *(const half8*)&Al[wr * 64 + f * 16 + fr][kg];
      bh[f] = *(const half8*)&Bh[wc * 64 + f * 16 + fr][kg];
      bl[f] = *(const half8*)&Bl[wc * 64 + f * 16 + fr][kg];
    }
#pragma unroll
    for (int fm = 0; fm < 4; ++fm)
#pragma unroll
      for (int fn = 0; fn < 4; ++fn) {
        acc[fm][fn] = __builtin_amdgcn_mfma_f32_16x16x32_f16(ah[fm], bh[fn], acc[fm][fn], 0, 0, 0);
        acc[fm][fn] = __builtin_amdgcn_mfma_f32_16x16x32_f16(ah[fm], bl[fn], acc[fm][fn], 0, 0, 0);
        acc[fm][fn] = __builtin_amdgcn_mfma_f32_16x16x32_f16(al[fm], bh[fn], acc[fm][fn], 0, 0, 0);
      }
  }
  const int rsub = (lane >> 4) << 2;
#pragma unroll
  for (int fm = 0; fm < 4; ++fm)
#pragma unroll
    for (int fn = 0; fn < 4; ++fn) {
      const int r0 = rowBase + wr * 64 + fm * 16 + rsub;
      const int c0 = colBase + wc * 64 + fn * 16 + fr;
#pragma unroll
      for (int r = 0; r < 4; ++r)
        Co[(size_t)(r0 + r) * P_CNT + c0] = acc[fm][fn][r];
    }
}

// ---------------- kernel P1: per-slice partials (2048 blocks, 8 per sample) ----------------
// Thread owns p_local(j) = 4*tid + 1024*(j>>2) + (j&3), j in [0,16); p = s*4096 + p_local.
__global__ __launch_bounds__(256) void persample1(
    const float* __restrict__ OUT, const int* __restrict__ cams,
    const int* __restrict__ prxArr,
    float* __restrict__ pmaxA, float* __restrict__ imA, float* __restrict__ isA,
    float* __restrict__ camV, int* __restrict__ camI,
    int* __restrict__ cxCnt, float* __restrict__ cxVal, int* __restrict__ cxIdx,
    int* __restrict__ smCnt, float* __restrict__ smVal, int* __restrict__ smIdx) {
  __shared__ __align__(16) int hist[256];
  __shared__ int ibc[2];
  __shared__ int lcnt;
  __shared__ float red4[4];
  __shared__ float mwS[4], swS[4];
  __shared__ float cvW[32]; __shared__ int ciW[32];

  const int blk = blockIdx.x;
  const int b = blk >> 3, s = blk & 7;
  const int tid = threadIdx.x, lane = tid & 63, wid = tid >> 6;
  const int sl = b * NSLICE + s;
  const float* Srow = OUT + (size_t)b * P_CNT + s * SLICE_N;
  const float* Mrow = OUT + (size_t)(B_SZ + b) * P_CNT + s * SLICE_N;
  const int pr = prxArr[b], cam = cams[b];
  const int gbase = s * SLICE_N + 4 * tid;

  // ---- load score slice (coalesced) ----
  float sc[16];
#pragma unroll
  for (int q = 0; q < 4; ++q) {
    float4 f = ((const float4*)Srow)[tid + 256 * q];
    sc[4 * q + 0] = f.x; sc[4 * q + 1] = f.y; sc[4 * q + 2] = f.z; sc[4 * q + 3] = f.w;
  }
  float mx = sc[0];
#pragma unroll
  for (int j = 1; j < 16; ++j) mx = fmaxf(mx, sc[j]);
  const float Mslice = blockMax4(mx, tid, red4);
  if (tid == 0) pmaxA[sl] = Mslice;

  // ---- intra partial: online LSE over {p : p%8 == cam} in this slice ----
  {
    const bool mine = ((tid & 1) == (cam >> 2));
    const int cc = cam & 3;
    float im = NEG_BIG, is = 0.f;
    if (mine) {
#pragma unroll
      for (int q = 0; q < 4; ++q) {
        float v = (cc == 0) ? sc[4 * q] : (cc == 1) ? sc[4 * q + 1]
                : (cc == 2) ? sc[4 * q + 2] : sc[4 * q + 3];
        if (v <= im) is += expf((v - im) * INVT);
        else { is = is * expf((im - v) * INVT) + 1.f; im = v; }
      }
    }
#pragma unroll
    for (int off = 1; off < 64; off <<= 1) {
      float m2 = __shfl_xor(im, off);
      float s2 = __shfl_xor(is, off);
      float Mx = fmaxf(im, m2);
      is = is * expf((im - Mx) * INVT) + s2 * expf((m2 - Mx) * INVT);
      im = Mx;
    }
    if (lane == 0) { mwS[wid] = im; swS[wid] = is; }
    __syncthreads();
    if (tid == 0) {
      float m0 = mwS[0], s0 = swS[0];
      for (int w = 1; w < 4; ++w) {
        float Mx = fmaxf(m0, mwS[w]);
        s0 = s0 * expf((m0 - Mx) * INVT) + swS[w] * expf((mwS[w] - Mx) * INVT);
        m0 = Mx;
      }
      imA[sl] = m0; isA[sl] = s0;
    }
    __syncthreads();
  }

  // ---- cross candidates: top-53 superset of slice minus pos range ----
  const int posBase = pr & ~7;
  auto cval = [&](int j) -> float {
    int p = gbase + ((j >> 2) << 10) + (j & 3);
    return ((unsigned)(p - posBase) < 8u) ? NEG_BIG : sc[j];
  };
  auto gidx = [&](int j) -> int { return gbase + ((j >> 2) << 10) + (j & 3); };
  selectCollect(cval, gidx, 53, Mslice, 2.0f, tid, lane, hist, ibc, &lcnt,
                cxVal + (size_t)sl * CAP, cxIdx + (size_t)sl * CAP, cxCnt + sl);

  // ---- sims slice ----
  float sm[16];
#pragma unroll
  for (int q = 0; q < 4; ++q) {
    float4 g = ((const float4*)Mrow)[tid + 256 * q];
    sm[4 * q + 0] = 0.15f * sc[4 * q + 0] + 0.85f * g.x;
    sm[4 * q + 1] = 0.15f * sc[4 * q + 1] + 0.85f * g.y;
    sm[4 * q + 2] = 0.15f * sc[4 * q + 2] + 0.85f * g.z;
    sm[4 * q + 3] = 0.15f * sc[4 * q + 3] + 0.85f * g.w;
  }

  // ---- per-cam argmax partial (thread parity covers 4 of 8 cams) ----
  {
    float cm[4]; int cix[4];
#pragma unroll
    for (int c = 0; c < 4; ++c) { cm[c] = NEG_BIG; cix[c] = 0x7fffffff; }
#pragma unroll
    for (int q = 0; q < 4; ++q)
#pragma unroll
      for (int c = 0; c < 4; ++c) {
        float v = sm[4 * q + c];
        int p = gbase + (q << 10) + c;
        if (v > cm[c]) { cm[c] = v; cix[c] = p; }
      }
    const bool odd = (tid & 1);
    float v8[8]; int i8[8];
#pragma unroll
    for (int c = 0; c < 4; ++c) {
      float ov = __shfl_xor(cm[c], 1); int oi = __shfl_xor(cix[c], 1);
      v8[c]     = odd ? ov : cm[c];   i8[c]     = odd ? oi : cix[c];
      v8[c + 4] = odd ? cm[c] : ov;   i8[c + 4] = odd ? cix[c] : oi;
    }
#pragma unroll
    for (int off = 2; off <= 32; off <<= 1)
#pragma unroll
      for (int c = 0; c < 8; ++c) {
        float vv = __shfl_xor(v8[c], off); int ii = __shfl_xor(i8[c], off);
        if (vv > v8[c] || (vv == v8[c] && ii < i8[c])) { v8[c] = vv; i8[c] = ii; }
      }
    if (lane < 8) {
#pragma unroll
      for (int c = 0; c < 8; ++c)
        if (lane == c) { cvW[wid * 8 + c] = v8[c]; ciW[wid * 8 + c] = i8[c]; }
    }
    __syncthreads();
    if (tid < 8) {
      float v = cvW[tid]; int ix = ciW[tid];
      for (int w = 1; w < 4; ++w) {
        float v2 = cvW[w * 8 + tid]; int i2 = ciW[w * 8 + tid];
        if (v2 > v || (v2 == v && i2 < ix)) { v = v2; ix = i2; }
      }
      camV[(size_t)sl * 8 + tid] = v; camI[(size_t)sl * 8 + tid] = ix;
    }
    __syncthreads();
  }

  // ---- sims candidates: top-56 superset of slice (exclusion happens in P2) ----
  float mx2 = sm[0];
#pragma unroll
  for (int j = 1; j < 16; ++j) mx2 = fmaxf(mx2, sm[j]);
  const float Ms = blockMax4(mx2, tid, red4);
  auto sval = [&](int j) -> float { return sm[j]; };
  selectCollect(sval, gidx, 56, Ms, 0.35f, tid, lane, hist, ibc, &lcnt,
                smVal + (size_t)sl * CAP, smIdx + (size_t)sl * CAP, smCnt + sl);
}

// ---------------- kernel P2: per-sample merge (256 blocks) ----------------
__global__ __launch_bounds__(256) void persample2(
    const float* __restrict__ OUT, const int* __restrict__ prxArr,
    const float* __restrict__ pmaxA, const float* __restrict__ imA,
    const float* __restrict__ isA,
    const float* __restrict__ camV, const int* __restrict__ camI,
    const int* __restrict__ cxCnt, const float* __restrict__ cxVal,
    const int* __restrict__ cxIdx,
    const int* __restrict__ smCnt, const float* __restrict__ smVal,
    const int* __restrict__ smIdx,
    float* __restrict__ intraArr, float* __restrict__ crossArr,
    float* __restrict__ onlArr) {
  __shared__ float vbuf[NSLICE * CAP];
  __shared__ int   ibuf[NSLICE * CAP];
  __shared__ int   offs[9];
  __shared__ float red4[4];
  __shared__ float MM[1];
  __shared__ float cv[8]; __shared__ int ci[8];
  __shared__ int   ch[3];
  __shared__ float sbuf[56];
  __shared__ int   scnt;

  const int b = blockIdx.x;
  const int tid = threadIdx.x;
  const float* Srow = OUT + (size_t)b * P_CNT;
  const int pr = prxArr[b];
  const int posBase = pr & ~7;

  // ---- global max ----
  if (tid < 8) {
    float v = pmaxA[b * NSLICE + tid];
#pragma unroll
    for (int off = 1; off < 8; off <<= 1) v = fmaxf(v, __shfl_xor(v, off));
    if (tid == 0) MM[0] = v;
  }
  // ---- cross offsets ----
  if (tid == 32) {
    int o = 0;
    for (int s = 0; s < NSLICE; ++s) { offs[s] = o; o += cxCnt[b * NSLICE + s]; }
    offs[8] = o;
  }
  // ---- intra merge ----
  if (tid == 64) {
    float m0 = imA[b * NSLICE], s0 = isA[b * NSLICE];
    for (int s = 1; s < NSLICE; ++s) {
      float m2 = imA[b * NSLICE + s], s2 = isA[b * NSLICE + s];
      float Mx = fmaxf(m0, m2);
      s0 = s0 * expf((m0 - Mx) * INVT) + s2 * expf((m2 - Mx) * INVT);
      m0 = Mx;
    }
    intraArr[b] = -((Srow[pr] - m0) * INVT - logf(s0));
  }
  __syncthreads();
  const float M = MM[0];
  const int C = offs[8];

  // ---- stage cross candidates ----
  for (int s = 0; s < NSLICE; ++s) {
    int o = offs[s], n = offs[s + 1] - o;
    for (int i = tid; i < n; i += 256) {
      vbuf[o + i] = cxVal[(size_t)(b * NSLICE + s) * CAP + i];
      ibuf[o + i] = cxIdx[(size_t)(b * NSLICE + s) * CAP + i];
    }
  }
  __syncthreads();
  // ---- exact rank -> top-50 -> LSE ----
  {
    float ve[4]; int ie[4]; int rk[4];
#pragma unroll
    for (int k = 0; k < 4; ++k) {
      int e = tid + 256 * k;
      ve[k] = (e < C) ? vbuf[e] : NEG_BIG;
      ie[k] = (e < C) ? ibuf[e] : 0x7fffffff;
      rk[k] = 0;
    }
    for (int m = 0; m < C; ++m) {
      float vm = vbuf[m]; int im = ibuf[m];
#pragma unroll
      for (int k = 0; k < 4; ++k)
        rk[k] += (vm > ve[k]) || (vm == ve[k] && im < ie[k]);
    }
    float myexp = 0.f;
#pragma unroll
    for (int k = 0; k < 4; ++k) {
      int e = tid + 256 * k;
      if (e < C && rk[k] < 50) myexp += expf((ve[k] - M) * INVT);
    }
    float pe = 0.f, pl = 0.f;
    if (tid < 8) {
      float pv = Srow[posBase + tid];
      pe = expf((pv - M) * INVT);
      pl = (pv - M) * INVT;
    }
    float stot = blockSum4(myexp + pe, tid, red4);
    float plin = blockSum4(pl, tid, red4);
    if (tid == 0) {
      float lse = logf(stot);
      crossArr[b] = -(plin - 8.f * lse) * 0.125f;
    }
  }

  // ---- cam merge -> top-3 cameras -> chosen indices ----
  if (tid < 8) {
    float v = camV[(size_t)(b * NSLICE) * 8 + tid];
    int  ix = camI[(size_t)(b * NSLICE) * 8 + tid];
    for (int s = 1; s < NSLICE; ++s) {
      float v2 = camV[(size_t)(b * NSLICE + s) * 8 + tid];
      int  i2 = camI[(size_t)(b * NSLICE + s) * 8 + tid];
      if (v2 > v || (v2 == v && i2 < ix)) { v = v2; ix = i2; }
    }
    cv[tid] = v; ci[tid] = ix;
  }
  // sims offsets (parallel with cam merge)
  if (tid == 32) {
    int o = 0;
    for (int s = 0; s < NSLICE; ++s) { offs[s] = o; o += smCnt[b * NSLICE + s]; }
    offs[8] = o;
  }
  __syncthreads();
  if (tid == 0) {
    unsigned used = 0;
    for (int k = 0; k < 3; ++k) {
      float best = NEG_BIG; int bc = 0;
      for (int c = 0; c < 8; ++c)
        if (!((used >> c) & 1u) && cv[c] > best) { best = cv[c]; bc = c; }
      used |= 1u << bc;
      ch[k] = ci[bc];
    }
    scnt = 0;
  }
  __syncthreads();
  const int c0 = ch[0], c1 = ch[1], c2 = ch[2];
  const int C2 = offs[8];

  // ---- stage sims candidates (mask chosen) ----
  for (int s = 0; s < NSLICE; ++s) {
    int o = offs[s], n = offs[s + 1] - o;
    for (int i = tid; i < n; i += 256) {
      float v = smVal[(size_t)(b * NSLICE + s) * CAP + i];
      int  ix = smIdx[(size_t)(b * NSLICE + s) * CAP + i];
      if (ix == c0 || ix == c1 || ix == c2) v = NEG_BIG;
      vbuf[o + i] = v; ibuf[o + i] = ix;
    }
  }
  __syncthreads();
  // ---- exact rank -> top-50 (excl chosen) -> gather scores -> LSE ----
  {
    float ve[4]; int ie[4]; int rk[4];
#pragma unroll
    for (int k = 0; k < 4; ++k) {
      int e = tid + 256 * k;
      ve[k] = (e < C2) ? vbuf[e] : NEG_BIG;
      ie[k] = (e < C2) ? ibuf[e] : 0x7fffffff;
      rk[k] = 0;
    }
    for (int m = 0; m < C2; ++m) {
      float vm = vbuf[m]; int im = ibuf[m];
#pragma unroll
      for (int k = 0; k < 4; ++k)
        rk[k] += (vm > ve[k]) || (vm == ve[k] && im < ie[k]);
    }
#pragma unroll
    for (int k = 0; k < 4; ++k) {
      int e = tid + 256 * k;
      if (e < C2 && ve[k] > -1.0e38f && rk[k] < 50) {
        int t = atomicAdd(&scnt, 1);
        if (t < 50) sbuf[t] = Srow[ie[k]];
      }
    }
    if (tid < 3) sbuf[50 + tid] = Srow[ch[tid]];
    __syncthreads();
    if (tid < 64) {
      float v = (tid < 53) ? sbuf[tid] : NEG_BIG;
      float mm = v;
#pragma unroll
      for (int off = 1; off < 64; off <<= 1) mm = fmaxf(mm, __shfl_xor(mm, off));
      float e = (tid < 53) ? expf((v - mm) * INVT) : 0.f;
      float ss = e;
#pragma unroll
      for (int off = 1; off < 64; off <<= 1) ss += __shfl_xor(ss, off);
      float lse = logf(ss);
      float c = (tid >= 50 && tid < 53) ? ((v - mm) * INVT - lse) : 0.f;
#pragma unroll
      for (int off = 1; off < 64; off <<= 1) c += __shfl_xor(c, off);
      if (tid == 0) onlArr[b] = -c * (1.0f / 3.0f);
    }
  }
}

// ---------------- kernel 3: per-camera means -> scalar ----------------
__global__ void finalize(const int* __restrict__ cams,
                         const float* __restrict__ ia,
                         const float* __restrict__ ca,
                         const float* __restrict__ oa,
                         float* __restrict__ out) {
  if (blockIdx.x == 0 && threadIdx.x == 0) {
    float s[8] = {}; float n[8] = {};
    for (int b = 0; b < B_SZ; ++b) {
      int c = cams[b];
      s[c] += ia[b] + ca[b] + oa[b];
      n[c] += 1.f;
    }
    float tot = 0.f;
    for (int c = 0; c < 8; ++c)
      if (n[c] > 0.f) tot += s[c] / n[c];
    out[0] = tot;
  }
}

extern "C" void kernel_launch(void* const* d_in, const int* in_sizes, int n_in,
                              void* d_out, int out_size, void* d_ws, size_t ws_size,
                              hipStream_t stream) {
  const float* features = (const float*)d_in[0];
  const int*   targets  = (const int*)d_in[1];
  const int*   cams     = (const int*)d_in[2];
  const float* mem      = (const float*)d_in[4];
  const int*   all_prx  = (const int*)d_in[6];

  float* ws = (float*)d_ws;
  float* A2  = ws;                               // 512*256
  float* OUT = ws + 512 * D_DIM;                 // 512*32768
  char*  tail = (char*)(OUT + (size_t)512 * P_CNT);

  int*   prxArr  = (int*)tail;                  tail += B_SZ * 4;
  float* intraArr = (float*)tail;               tail += B_SZ * 4;
  float* crossArr = (float*)tail;               tail += B_SZ * 4;
  float* onlArr   = (float*)tail;               tail += B_SZ * 4;
  float* pmaxA = (float*)tail;                  tail += B_SZ * NSLICE * 4;
  float* imA   = (float*)tail;                  tail += B_SZ * NSLICE * 4;
  float* isA   = (float*)tail;                  tail += B_SZ * NSLICE * 4;
  float* camV  = (float*)tail;                  tail += B_SZ * NSLICE * 8 * 4;
  int*   camI  = (int*)tail;                    tail += B_SZ * NSLICE * 8 * 4;
  int*   cxCnt = (int*)tail;                    tail += B_SZ * NSLICE * 4;
  int*   smCnt = (int*)tail;                    tail += B_SZ * NSLICE * 4;
  float* cxVal = (float*)tail;                  tail += (size_t)B_SZ * NSLICE * CAP * 4;
  int*   cxIdx = (int*)tail;                    tail += (size_t)B_SZ * NSLICE * CAP * 4;
  float* smVal = (float*)tail;                  tail += (size_t)B_SZ * NSLICE * CAP * 4;
  int*   smIdx = (int*)tail;                    tail += (size_t)B_SZ * NSLICE * CAP * 4;

  prep_kernel<<<B_SZ, D_DIM, 0, stream>>>(features, targets, all_prx, mem, A2, prxArr);
  gemm_mfma<<<1024, 256, 0, stream>>>(A2, mem, OUT);
  persample1<<<B_SZ * NSLICE, 256, 0, stream>>>(OUT, cams, prxArr,
      pmaxA, imA, isA, camV, camI, cxCnt, cxVal, cxIdx, smCnt, smVal, smIdx);
  persample2<<<B_SZ, 256, 0, stream>>>(OUT, prxArr,
      pmaxA, imA, isA, camV, camI, cxCnt, cxVal, cxIdx, smCnt, smVal, smIdx,
      intraArr, crossArr, onlArr);
  finalize<<<1, 64, 0, stream>>>(cams, intraArr, crossArr, onlArr, (float*)d_out);
}

// Round 11
// 256.671 us; speedup vs baseline: 1.0824x; 1.0824x over previous
//
#include <hip/hip_runtime.h>

#define P_CNT 32768
#define D_DIM 256
#define B_SZ  256
#define INVT  20.0f          // 1/TEMP
#define NEG_BIG -3.0e38f
#define SLICE_N 4096
#define NSLICE 8
#define CAP 128

typedef _Float16 half8  __attribute__((ext_vector_type(8)));
typedef _Float16 half4v __attribute__((ext_vector_type(4)));
typedef float    floatx4 __attribute__((ext_vector_type(4)));

// ---------------- 4-wave (256-thread) block reductions ----------------
__device__ __forceinline__ float blockMax4(float v, int tid, float* red4) {
#pragma unroll
  for (int off = 1; off < 64; off <<= 1) v = fmaxf(v, __shfl_xor(v, off));
  if ((tid & 63) == 0) red4[tid >> 6] = v;
  __syncthreads();
  float r = fmaxf(fmaxf(red4[0], red4[1]), fmaxf(red4[2], red4[3]));
  __syncthreads();
  return r;
}

__device__ __forceinline__ float blockSum4(float v, int tid, float* red4) {
#pragma unroll
  for (int off = 1; off < 64; off <<= 1) v += __shfl_xor(v, off);
  if ((tid & 63) == 0) red4[tid >> 6] = v;
  __syncthreads();
  float r = red4[0] + red4[1] + red4[2] + red4[3];
  __syncthreads();
  return r;
}

// ---------------- per-slice candidate superset collect ----------------
// Collects ALL elements in the smallest tail bin-range whose count >= K
// (a superset of the slice's top-K). 256 EW bins over [hi-range, hi],
// bin 0 = bulk (never counted, never collected). Exact ranking happens in P2.
template <typename GetV, typename GetI>
__device__ void selectCollect(GetV getv, GetI geti, int K, float hi, float range0,
                              int tid, int lane,
                              int* hist, int* ibc, int* lcnt,
                              float* oVal, int* oIdx, int* oCnt) {
  float range = range0;
  for (int guard = 0; guard < 10; ++guard) {
    const float lo = hi - range;
    const float scale = 256.0f / range;
    hist[tid] = 0;
    if (tid == 0) ibc[0] = -1;
    __syncthreads();
#pragma unroll
    for (int j = 0; j < 16; ++j) {
      float v = getv(j);
      float t = (v - lo) * scale;
      int bin = (int)fminf(fmaxf(t, 0.0f), 255.0f);
      if (bin >= 1) atomicAdd(&hist[bin], 1);
    }
    __syncthreads();
    if (tid < 64) {
      int4 h = ((const int4*)hist)[tid];
      if (tid == 0) h.x = 0;                       // exclude bulk bin 0
      int L = h.x + h.y + h.z + h.w;
      int S = L;
#pragma unroll
      for (int off = 1; off < 64; off <<= 1) {
        int y = __shfl_down(S, off);
        S += (lane + off < 64) ? y : 0;
      }
      int total = __shfl(S, 0);
      if (total >= K) {
        int above = S - L;                          // count in bins > 4*tid+3
        if (above < K && S >= K) {                  // unique boundary lane
          int a = above, bsel;
          if (a + h.w >= K) bsel = 4 * tid + 3;
          else { a += h.w;
            if (a + h.z >= K) bsel = 4 * tid + 2;
            else { a += h.z;
              if (a + h.y >= K) bsel = 4 * tid + 1;
              else bsel = 4 * tid;                  // S>=K guarantees this
            } }
          ibc[0] = bsel;
        }
      }
    }
    __syncthreads();
    if (ibc[0] >= 0) {
      const int Bstar = ibc[0];
      if (tid == 0) *lcnt = 0;
      __syncthreads();
#pragma unroll
      for (int j = 0; j < 16; ++j) {
        float v = getv(j);
        float t = (v - lo) * scale;
        int bin = (int)fminf(fmaxf(t, 0.0f), 255.0f);
        if (bin >= Bstar) {
          int tt = atomicAdd(lcnt, 1);
          if (tt < CAP) { oVal[tt] = v; oIdx[tt] = geti(j); }
        }
      }
      __syncthreads();
      if (tid == 0) *oCnt = min(*lcnt, CAP);
      return;
    }
    range *= 4.0f;                                  // tail too sparse: extend
    __syncthreads();
  }
  if (tid == 0) *oCnt = 0;                          // unreachable for real data
}

// ---------------- kernel 0: gather prx, build A' = [features; mem[prx]] ----------------
__global__ void prep_kernel(const float* __restrict__ features,
                            const int* __restrict__ targets,
                            const int* __restrict__ all_prx,
                            const float* __restrict__ mem,
                            float* __restrict__ A2,
                            int* __restrict__ prxArr) {
  const int b = blockIdx.x;
  const int k = threadIdx.x;
  const int t = targets[b];
  const int pr = all_prx[t];
  if (k == 0) prxArr[b] = pr;
  A2[b * D_DIM + k] = features[b * D_DIM + k];
  A2[(B_SZ + b) * D_DIM + k] = mem[(size_t)pr * D_DIM + k];
}

// ---------------- kernel 1: split-fp16 3-pass MFMA GEMM ----------------
__global__ __launch_bounds__(256) void gemm_mfma(const float* __restrict__ A,
                                                 const float* __restrict__ Bm,
                                                 float* __restrict__ Co) {
  __shared__ _Float16 Ah[128][32], Al[128][32], Bh[128][32], Bl[128][32];
  const int tid = threadIdx.x;
  const int lane = tid & 63;
  const int wid = tid >> 6;
  const int wr = wid >> 1, wc = wid & 1;
  const int orig = (blockIdx.x & 7) * 128 + (blockIdx.x >> 3);
  const int rowBase = (orig & 3) << 7;
  const int colBase = (orig >> 2) << 7;

  const int trow = tid >> 3;
  const int tseg = tid & 7;

  floatx4 acc[4][4];
#pragma unroll
  for (int i = 0; i < 4; ++i)
#pragma unroll
    for (int j = 0; j < 4; ++j) {
      acc[i][j][0] = 0.f; acc[i][j][1] = 0.f; acc[i][j][2] = 0.f; acc[i][j][3] = 0.f;
    }

  const int fr = lane & 15;
  const int kg = (lane >> 4) << 3;

  for (int step = 0; step < 8; ++step) {
    const int k0 = step << 5;
    float4 sa[4], sb[4];
#pragma unroll
    for (int p = 0; p < 4; ++p) {
      const int r = trow + (p << 5);
      sa[p] = *(const float4*)(A  + (size_t)(rowBase + r) * D_DIM + k0 + tseg * 4);
      sb[p] = *(const float4*)(Bm + (size_t)(colBase + r) * D_DIM + k0 + tseg * 4);
    }
    __syncthreads();
#pragma unroll
    for (int p = 0; p < 4; ++p) {
      const int r = trow + (p << 5);
      float4 v = sa[p];
      half4v h, l;
      h[0] = (_Float16)v.x; l[0] = (_Float16)(v.x - (float)h[0]);
      h[1] = (_Float16)v.y; l[1] = (_Float16)(v.y - (float)h[1]);
      h[2] = (_Float16)v.z; l[2] = (_Float16)(v.z - (float)h[2]);
      h[3] = (_Float16)v.w; l[3] = (_Float16)(v.w - (float)h[3]);
      *(half4v*)&Ah[r][tseg * 4] = h;
      *(half4v*)&Al[r][tseg * 4] = l;
      v = sb[p];
      h[0] = (_Float16)v.x; l[0] = (_Float16)(v.x - (float)h[0]);
      h[1] = (_Float16)v.y; l[1] = (_Float16)(v.y - (float)h[1]);
      h[2] = (_Float16)v.z; l[2] = (_Float16)(v.z - (float)h[2]);
      h[3] = (_Float16)v.w; l[3] = (_Float16)(v.w - (float)h[3]);
      *(half4v*)&Bh[r][tseg * 4] = h;
      *(half4v*)&Bl[r][tseg * 4] = l;
    }
    __syncthreads();
    half8 ah[4], al[4], bh[4], bl[4];
#pragma unroll
    for (int f = 0; f < 4; ++f) {
      ah[f] = *(const half8*)&Ah[wr * 64 + f * 16 + fr][kg];
      al[f] = *(const half8*)&Al[wr * 64 + f * 16 + fr][kg];
      bh[f] = *(const half8*)&Bh[wc * 64 + f * 16 + fr][kg];
      bl[f] = *(const half8*)&Bl[wc * 64 + f * 16 + fr][kg];
    }
#pragma unroll
    for (int fm = 0; fm < 4; ++fm)
#pragma unroll
      for (int fn = 0; fn < 4; ++fn) {
        acc[fm][fn] = __builtin_amdgcn_mfma_f32_16x16x32_f16(ah[fm], bh[fn], acc[fm][fn], 0, 0, 0);
        acc[fm][fn] = __builtin_amdgcn_mfma_f32_16x16x32_f16(ah[fm], bl[fn], acc[fm][fn], 0, 0, 0);
        acc[fm][fn] = __builtin_amdgcn_mfma_f32_16x16x32_f16(al[fm], bh[fn], acc[fm][fn], 0, 0, 0);
      }
  }
  const int rsub = (lane >> 4) << 2;
#pragma unroll
  for (int fm = 0; fm < 4; ++fm)
#pragma unroll
    for (int fn = 0; fn < 4; ++fn) {
      const int r0 = rowBase + wr * 64 + fm * 16 + rsub;
      const int c0 = colBase + wc * 64 + fn * 16 + fr;
#pragma unroll
      for (int r = 0; r < 4; ++r)
        Co[(size_t)(r0 + r) * P_CNT + c0] = acc[fm][fn][r];
    }
}

// ---------------- kernel P1: per-slice partials (2048 blocks, 8 per sample) ----------------
// Thread owns p_local(j) = 4*tid + 1024*(j>>2) + (j&3), j in [0,16); p = s*4096 + p_local.
__global__ __launch_bounds__(256) void persample1(
    const float* __restrict__ OUT, const int* __restrict__ cams,
    const int* __restrict__ prxArr,
    float* __restrict__ pmaxA, float* __restrict__ imA, float* __restrict__ isA,
    float* __restrict__ camV, int* __restrict__ camI,
    int* __restrict__ cxCnt, float* __restrict__ cxVal, int* __restrict__ cxIdx,
    int* __restrict__ smCnt, float* __restrict__ smVal, int* __restrict__ smIdx) {
  __shared__ __align__(16) int hist[256];
  __shared__ int ibc[2];
  __shared__ int lcnt;
  __shared__ float red4[4];
  __shared__ float mwS[4], swS[4];
  __shared__ float cvW[32]; __shared__ int ciW[32];

  const int blk = blockIdx.x;
  const int b = blk >> 3, s = blk & 7;
  const int tid = threadIdx.x, lane = tid & 63, wid = tid >> 6;
  const int sl = b * NSLICE + s;
  const float* Srow = OUT + (size_t)b * P_CNT + s * SLICE_N;
  const float* Mrow = OUT + (size_t)(B_SZ + b) * P_CNT + s * SLICE_N;
  const int pr = prxArr[b], cam = cams[b];
  const int gbase = s * SLICE_N + 4 * tid;

  // ---- load score slice (coalesced) ----
  float sc[16];
#pragma unroll
  for (int q = 0; q < 4; ++q) {
    float4 f = ((const float4*)Srow)[tid + 256 * q];
    sc[4 * q + 0] = f.x; sc[4 * q + 1] = f.y; sc[4 * q + 2] = f.z; sc[4 * q + 3] = f.w;
  }
  float mx = sc[0];
#pragma unroll
  for (int j = 1; j < 16; ++j) mx = fmaxf(mx, sc[j]);
  const float Mslice = blockMax4(mx, tid, red4);
  if (tid == 0) pmaxA[sl] = Mslice;

  // ---- intra partial: online LSE over {p : p%8 == cam} in this slice ----
  {
    const bool mine = ((tid & 1) == (cam >> 2));
    const int cc = cam & 3;
    float im = NEG_BIG, is = 0.f;
    if (mine) {
#pragma unroll
      for (int q = 0; q < 4; ++q) {
        float v = (cc == 0) ? sc[4 * q] : (cc == 1) ? sc[4 * q + 1]
                : (cc == 2) ? sc[4 * q + 2] : sc[4 * q + 3];
        if (v <= im) is += expf((v - im) * INVT);
        else { is = is * expf((im - v) * INVT) + 1.f; im = v; }
      }
    }
#pragma unroll
    for (int off = 1; off < 64; off <<= 1) {
      float m2 = __shfl_xor(im, off);
      float s2 = __shfl_xor(is, off);
      float Mx = fmaxf(im, m2);
      is = is * expf((im - Mx) * INVT) + s2 * expf((m2 - Mx) * INVT);
      im = Mx;
    }
    if (lane == 0) { mwS[wid] = im; swS[wid] = is; }
    __syncthreads();
    if (tid == 0) {
      float m0 = mwS[0], s0 = swS[0];
      for (int w = 1; w < 4; ++w) {
        float Mx = fmaxf(m0, mwS[w]);
        s0 = s0 * expf((m0 - Mx) * INVT) + swS[w] * expf((mwS[w] - Mx) * INVT);
        m0 = Mx;
      }
      imA[sl] = m0; isA[sl] = s0;
    }
    __syncthreads();
  }

  // ---- cross candidates: top-53 superset of slice minus pos range ----
  const int posBase = pr & ~7;
  auto cval = [&](int j) -> float {
    int p = gbase + ((j >> 2) << 10) + (j & 3);
    return ((unsigned)(p - posBase) < 8u) ? NEG_BIG : sc[j];
  };
  auto gidx = [&](int j) -> int { return gbase + ((j >> 2) << 10) + (j & 3); };
  selectCollect(cval, gidx, 53, Mslice, 2.0f, tid, lane, hist, ibc, &lcnt,
                cxVal + (size_t)sl * CAP, cxIdx + (size_t)sl * CAP, cxCnt + sl);

  // ---- sims slice ----
  float sm[16];
#pragma unroll
  for (int q = 0; q < 4; ++q) {
    float4 g = ((const float4*)Mrow)[tid + 256 * q];
    sm[4 * q + 0] = 0.15f * sc[4 * q + 0] + 0.85f * g.x;
    sm[4 * q + 1] = 0.15f * sc[4 * q + 1] + 0.85f * g.y;
    sm[4 * q + 2] = 0.15f * sc[4 * q + 2] + 0.85f * g.z;
    sm[4 * q + 3] = 0.15f * sc[4 * q + 3] + 0.85f * g.w;
  }

  // ---- per-cam argmax partial (thread parity covers 4 of 8 cams) ----
  {
    float cm[4]; int cix[4];
#pragma unroll
    for (int c = 0; c < 4; ++c) { cm[c] = NEG_BIG; cix[c] = 0x7fffffff; }
#pragma unroll
    for (int q = 0; q < 4; ++q)
#pragma unroll
      for (int c = 0; c < 4; ++c) {
        float v = sm[4 * q + c];
        int p = gbase + (q << 10) + c;
        if (v > cm[c]) { cm[c] = v; cix[c] = p; }
      }
    const bool odd = (tid & 1);
    float v8[8]; int i8[8];
#pragma unroll
    for (int c = 0; c < 4; ++c) {
      float ov = __shfl_xor(cm[c], 1); int oi = __shfl_xor(cix[c], 1);
      v8[c]     = odd ? ov : cm[c];   i8[c]     = odd ? oi : cix[c];
      v8[c + 4] = odd ? cm[c] : ov;   i8[c + 4] = odd ? cix[c] : oi;
    }
#pragma unroll
    for (int off = 2; off <= 32; off <<= 1)
#pragma unroll
      for (int c = 0; c < 8; ++c) {
        float vv = __shfl_xor(v8[c], off); int ii = __shfl_xor(i8[c], off);
        if (vv > v8[c] || (vv == v8[c] && ii < i8[c])) { v8[c] = vv; i8[c] = ii; }
      }
    if (lane < 8) {
#pragma unroll
      for (int c = 0; c < 8; ++c)
        if (lane == c) { cvW[wid * 8 + c] = v8[c]; ciW[wid * 8 + c] = i8[c]; }
    }
    __syncthreads();
    if (tid < 8) {
      float v = cvW[tid]; int ix = ciW[tid];
      for (int w = 1; w < 4; ++w) {
        float v2 = cvW[w * 8 + tid]; int i2 = ciW[w * 8 + tid];
        if (v2 > v || (v2 == v && i2 < ix)) { v = v2; ix = i2; }
      }
      camV[(size_t)sl * 8 + tid] = v; camI[(size_t)sl * 8 + tid] = ix;
    }
    __syncthreads();
  }

  // ---- sims candidates: top-56 superset of slice (exclusion happens in P2) ----
  float mx2 = sm[0];
#pragma unroll
  for (int j = 1; j < 16; ++j) mx2 = fmaxf(mx2, sm[j]);
  const float Ms = blockMax4(mx2, tid, red4);
  auto sval = [&](int j) -> float { return sm[j]; };
  selectCollect(sval, gidx, 56, Ms, 0.35f, tid, lane, hist, ibc, &lcnt,
                smVal + (size_t)sl * CAP, smIdx + (size_t)sl * CAP, smCnt + sl);
}

// ---------------- kernel P2: per-sample merge (256 blocks) ----------------
__global__ __launch_bounds__(256) void persample2(
    const float* __restrict__ OUT, const int* __restrict__ prxArr,
    const float* __restrict__ pmaxA, const float* __restrict__ imA,
    const float* __restrict__ isA,
    const float* __restrict__ camV, const int* __restrict__ camI,
    const int* __restrict__ cxCnt, const float* __restrict__ cxVal,
    const int* __restrict__ cxIdx,
    const int* __restrict__ smCnt, const float* __restrict__ smVal,
    const int* __restrict__ smIdx,
    float* __restrict__ intraArr, float* __restrict__ crossArr,
    float* __restrict__ onlArr) {
  __shared__ __align__(16) float vbuf[NSLICE * CAP];
  __shared__ __align__(16) int   ibuf[NSLICE * CAP];
  __shared__ int   offs[9];
  __shared__ float red4[4];
  __shared__ float MM[1];
  __shared__ float cv[8]; __shared__ int ci[8];
  __shared__ int   ch[3];
  __shared__ float sbuf[56];
  __shared__ int   scnt;

  const int b = blockIdx.x;
  const int tid = threadIdx.x;
  const float* Srow = OUT + (size_t)b * P_CNT;
  const int pr = prxArr[b];
  const int posBase = pr & ~7;

  // ---- global max ----
  if (tid < 8) {
    float v = pmaxA[b * NSLICE + tid];
#pragma unroll
    for (int off = 1; off < 8; off <<= 1) v = fmaxf(v, __shfl_xor(v, off));
    if (tid == 0) MM[0] = v;
  }
  // ---- cross offsets ----
  if (tid == 32) {
    int o = 0;
    for (int s = 0; s < NSLICE; ++s) { offs[s] = o; o += cxCnt[b * NSLICE + s]; }
    offs[8] = o;
  }
  // ---- intra merge ----
  if (tid == 64) {
    float m0 = imA[b * NSLICE], s0 = isA[b * NSLICE];
    for (int s = 1; s < NSLICE; ++s) {
      float m2 = imA[b * NSLICE + s], s2 = isA[b * NSLICE + s];
      float Mx = fmaxf(m0, m2);
      s0 = s0 * expf((m0 - Mx) * INVT) + s2 * expf((m2 - Mx) * INVT);
      m0 = Mx;
    }
    intraArr[b] = -((Srow[pr] - m0) * INVT - logf(s0));
  }
  __syncthreads();
  const float M = MM[0];
  const int C = offs[8];
  const int Cp = (C + 3) & ~3;

  // ---- stage cross candidates (+ sentinel pad to multiple of 4) ----
  for (int s = 0; s < NSLICE; ++s) {
    int o = offs[s], n = offs[s + 1] - o;
    for (int i = tid; i < n; i += 256) {
      vbuf[o + i] = cxVal[(size_t)(b * NSLICE + s) * CAP + i];
      ibuf[o + i] = cxIdx[(size_t)(b * NSLICE + s) * CAP + i];
    }
  }
  if (tid < Cp - C) { vbuf[C + tid] = NEG_BIG; ibuf[C + tid] = 0x7fffffff; }
  __syncthreads();
  // ---- exact rank (vectorized b128 sweeps) -> top-50 -> LSE ----
  {
    float ve[4]; int ie[4]; int rk[4];
#pragma unroll
    for (int k = 0; k < 4; ++k) {
      int e = tid + 256 * k;
      ve[k] = (e < C) ? vbuf[e] : NEG_BIG;
      ie[k] = (e < C) ? ibuf[e] : 0x7fffffff;
      rk[k] = 0;
    }
    const float4* v4 = (const float4*)vbuf;
    const int4*   q4 = (const int4*)ibuf;
    for (int m4 = 0; m4 < (Cp >> 2); ++m4) {
      float4 vm = v4[m4]; int4 im = q4[m4];
#pragma unroll
      for (int k = 0; k < 4; ++k) {
        rk[k] += (vm.x > ve[k]) || (vm.x == ve[k] && im.x < ie[k]);
        rk[k] += (vm.y > ve[k]) || (vm.y == ve[k] && im.y < ie[k]);
        rk[k] += (vm.z > ve[k]) || (vm.z == ve[k] && im.z < ie[k]);
        rk[k] += (vm.w > ve[k]) || (vm.w == ve[k] && im.w < ie[k]);
      }
    }
    float myexp = 0.f;
#pragma unroll
    for (int k = 0; k < 4; ++k) {
      int e = tid + 256 * k;
      if (e < C && rk[k] < 50) myexp += expf((ve[k] - M) * INVT);
    }
    float pe = 0.f, pl = 0.f;
    if (tid < 8) {
      float pv = Srow[posBase + tid];
      pe = expf((pv - M) * INVT);
      pl = (pv - M) * INVT;
    }
    float stot = blockSum4(myexp + pe, tid, red4);
    float plin = blockSum4(pl, tid, red4);
    if (tid == 0) {
      float lse = logf(stot);
      crossArr[b] = -(plin - 8.f * lse) * 0.125f;
    }
  }

  // ---- cam merge -> top-3 cameras -> chosen indices ----
  if (tid < 8) {
    float v = camV[(size_t)(b * NSLICE) * 8 + tid];
    int  ix = camI[(size_t)(b * NSLICE) * 8 + tid];
    for (int s = 1; s < NSLICE; ++s) {
      float v2 = camV[(size_t)(b * NSLICE + s) * 8 + tid];
      int  i2 = camI[(size_t)(b * NSLICE + s) * 8 + tid];
      if (v2 > v || (v2 == v && i2 < ix)) { v = v2; ix = i2; }
    }
    cv[tid] = v; ci[tid] = ix;
  }
  // sims offsets (parallel with cam merge)
  if (tid == 32) {
    int o = 0;
    for (int s = 0; s < NSLICE; ++s) { offs[s] = o; o += smCnt[b * NSLICE + s]; }
    offs[8] = o;
  }
  __syncthreads();
  if (tid == 0) {
    unsigned used = 0;
    for (int k = 0; k < 3; ++k) {
      float best = NEG_BIG; int bc = 0;
      for (int c = 0; c < 8; ++c)
        if (!((used >> c) & 1u) && cv[c] > best) { best = cv[c]; bc = c; }
      used |= 1u << bc;
      ch[k] = ci[bc];
    }
    scnt = 0;
  }
  __syncthreads();
  const int c0 = ch[0], c1 = ch[1], c2 = ch[2];
  const int C2 = offs[8];
  const int C2p = (C2 + 3) & ~3;

  // ---- stage sims candidates (mask chosen; + sentinel pad) ----
  for (int s = 0; s < NSLICE; ++s) {
    int o = offs[s], n = offs[s + 1] - o;
    for (int i = tid; i < n; i += 256) {
      float v = smVal[(size_t)(b * NSLICE + s) * CAP + i];
      int  ix = smIdx[(size_t)(b * NSLICE + s) * CAP + i];
      if (ix == c0 || ix == c1 || ix == c2) v = NEG_BIG;
      vbuf[o + i] = v; ibuf[o + i] = ix;
    }
  }
  if (tid < C2p - C2) { vbuf[C2 + tid] = NEG_BIG; ibuf[C2 + tid] = 0x7fffffff; }
  __syncthreads();
  // ---- exact rank (vectorized) -> top-50 (excl chosen) -> gather -> LSE ----
  {
    float ve[4]; int ie[4]; int rk[4];
#pragma unroll
    for (int k = 0; k < 4; ++k) {
      int e = tid + 256 * k;
      ve[k] = (e < C2) ? vbuf[e] : NEG_BIG;
      ie[k] = (e < C2) ? ibuf[e] : 0x7fffffff;
      rk[k] = 0;
    }
    const float4* v4 = (const float4*)vbuf;
    const int4*   q4 = (const int4*)ibuf;
    for (int m4 = 0; m4 < (C2p >> 2); ++m4) {
      float4 vm = v4[m4]; int4 im = q4[m4];
#pragma unroll
      for (int k = 0; k < 4; ++k) {
        rk[k] += (vm.x > ve[k]) || (vm.x == ve[k] && im.x < ie[k]);
        rk[k] += (vm.y > ve[k]) || (vm.y == ve[k] && im.y < ie[k]);
        rk[k] += (vm.z > ve[k]) || (vm.z == ve[k] && im.z < ie[k]);
        rk[k] += (vm.w > ve[k]) || (vm.w == ve[k] && im.w < ie[k]);
      }
    }
#pragma unroll
    for (int k = 0; k < 4; ++k) {
      int e = tid + 256 * k;
      if (e < C2 && ve[k] > -1.0e38f && rk[k] < 50) {
        int t = atomicAdd(&scnt, 1);
        if (t < 50) sbuf[t] = Srow[ie[k]];
      }
    }
    if (tid < 3) sbuf[50 + tid] = Srow[ch[tid]];
    __syncthreads();
    if (tid < 64) {
      float v = (tid < 53) ? sbuf[tid] : NEG_BIG;
      float mm = v;
#pragma unroll
      for (int off = 1; off < 64; off <<= 1) mm = fmaxf(mm, __shfl_xor(mm, off));
      float e = (tid < 53) ? expf((v - mm) * INVT) : 0.f;
      float ss = e;
#pragma unroll
      for (int off = 1; off < 64; off <<= 1) ss += __shfl_xor(ss, off);
      float lse = logf(ss);
      float c = (tid >= 50 && tid < 53) ? ((v - mm) * INVT - lse) : 0.f;
#pragma unroll
      for (int off = 1; off < 64; off <<= 1) c += __shfl_xor(c, off);
      if (tid == 0) onlArr[b] = -c * (1.0f / 3.0f);
    }
  }
}

// ---------------- kernel 3: per-camera means -> scalar ----------------
__global__ void finalize(const int* __restrict__ cams,
                         const float* __restrict__ ia,
                         const float* __restrict__ ca,
                         const float* __restrict__ oa,
                         float* __restrict__ out) {
  if (blockIdx.x == 0 && threadIdx.x == 0) {
    float s[8] = {}; float n[8] = {};
    for (int b = 0; b < B_SZ; ++b) {
      int c = cams[b];
      s[c] += ia[b] + ca[b] + oa[b];
      n[c] += 1.f;
    }
    float tot = 0.f;
    for (int c = 0; c < 8; ++c)
      if (n[c] > 0.f) tot += s[c] / n[c];
    out[0] = tot;
  }
}

extern "C" void kernel_launch(void* const* d_in, const int* in_sizes, int n_in,
                              void* d_out, int out_size, void* d_ws, size_t ws_size,
                              hipStream_t stream) {
  const float* features = (const float*)d_in[0];
  const int*   targets  = (const int*)d_in[1];
  const int*   cams     = (const int*)d_in[2];
  const float* mem      = (const float*)d_in[4];
  const int*   all_prx  = (const int*)d_in[6];

  float* ws = (float*)d_ws;
  float* A2  = ws;                               // 512*256
  float* OUT = ws + 512 * D_DIM;                 // 512*32768
  char*  tail = (char*)(OUT + (size_t)512 * P_CNT);

  int*   prxArr  = (int*)tail;                  tail += B_SZ * 4;
  float* intraArr = (float*)tail;               tail += B_SZ * 4;
  float* crossArr = (float*)tail;               tail += B_SZ * 4;
  float* onlArr   = (float*)tail;               tail += B_SZ * 4;
  float* pmaxA = (float*)tail;                  tail += B_SZ * NSLICE * 4;
  float* imA   = (float*)tail;                  tail += B_SZ * NSLICE * 4;
  float* isA   = (float*)tail;                  tail += B_SZ * NSLICE * 4;
  float* camV  = (float*)tail;                  tail += B_SZ * NSLICE * 8 * 4;
  int*   camI  = (int*)tail;                    tail += B_SZ * NSLICE * 8 * 4;
  int*   cxCnt = (int*)tail;                    tail += B_SZ * NSLICE * 4;
  int*   smCnt = (int*)tail;                    tail += B_SZ * NSLICE * 4;
  float* cxVal = (float*)tail;                  tail += (size_t)B_SZ * NSLICE * CAP * 4;
  int*   cxIdx = (int*)tail;                    tail += (size_t)B_SZ * NSLICE * CAP * 4;
  float* smVal = (float*)tail;                  tail += (size_t)B_SZ * NSLICE * CAP * 4;
  int*   smIdx = (int*)tail;                    tail += (size_t)B_SZ * NSLICE * CAP * 4;

  prep_kernel<<<B_SZ, D_DIM, 0, stream>>>(features, targets, all_prx, mem, A2, prxArr);
  gemm_mfma<<<1024, 256, 0, stream>>>(A2, mem, OUT);
  persample1<<<B_SZ * NSLICE, 256, 0, stream>>>(OUT, cams, prxArr,
      pmaxA, imA, isA, camV, camI, cxCnt, cxVal, cxIdx, smCnt, smVal, smIdx);
  persample2<<<B_SZ, 256, 0, stream>>>(OUT, prxArr,
      pmaxA, imA, isA, camV, camI, cxCnt, cxVal, cxIdx, smCnt, smVal, smIdx,
      intraArr, crossArr, onlArr);
  finalize<<<1, 64, 0, stream>>>(cams, intraArr, crossArr, onlArr, (float*)d_out);
}

// Round 12
// 160.098 us; speedup vs baseline: 1.7353x; 1.6032x over previous
//
#include <hip/hip_runtime.h>

#define P_CNT 32768
#define D_DIM 256
#define B_SZ  256
#define INVT  20.0f          // 1/TEMP
#define NEG_BIG -3.0e38f
#define SLICE_N 4096
#define NSLICE 8
#define CAP 128

typedef _Float16 half8  __attribute__((ext_vector_type(8)));
typedef _Float16 half4v __attribute__((ext_vector_type(4)));
typedef float    floatx4 __attribute__((ext_vector_type(4)));

// ---------------- 4-wave (256-thread) block reductions ----------------
__device__ __forceinline__ float blockMax4(float v, int tid, float* red4) {
#pragma unroll
  for (int off = 1; off < 64; off <<= 1) v = fmaxf(v, __shfl_xor(v, off));
  if ((tid & 63) == 0) red4[tid >> 6] = v;
  __syncthreads();
  float r = fmaxf(fmaxf(red4[0], red4[1]), fmaxf(red4[2], red4[3]));
  __syncthreads();
  return r;
}

// ---------------- per-slice candidate superset collect (P1) ----------------
template <typename GetV, typename GetI>
__device__ void selectCollect(GetV getv, GetI geti, int K, float hi, float range0,
                              int tid, int lane,
                              int* hist, int* ibc, int* lcnt,
                              float* oVal, int* oIdx, int* oCnt) {
  float range = range0;
  for (int guard = 0; guard < 10; ++guard) {
    const float lo = hi - range;
    const float scale = 256.0f / range;
    hist[tid] = 0;
    if (tid == 0) ibc[0] = -1;
    __syncthreads();
#pragma unroll
    for (int j = 0; j < 16; ++j) {
      float v = getv(j);
      float t = (v - lo) * scale;
      int bin = (int)fminf(fmaxf(t, 0.0f), 255.0f);
      if (bin >= 1) atomicAdd(&hist[bin], 1);
    }
    __syncthreads();
    if (tid < 64) {
      int4 h = ((const int4*)hist)[tid];
      if (tid == 0) h.x = 0;
      int L = h.x + h.y + h.z + h.w;
      int S = L;
#pragma unroll
      for (int off = 1; off < 64; off <<= 1) {
        int y = __shfl_down(S, off);
        S += (lane + off < 64) ? y : 0;
      }
      int total = __shfl(S, 0);
      if (total >= K) {
        int above = S - L;
        if (above < K && S >= K) {
          int a = above, bsel;
          if (a + h.w >= K) bsel = 4 * tid + 3;
          else { a += h.w;
            if (a + h.z >= K) bsel = 4 * tid + 2;
            else { a += h.z;
              if (a + h.y >= K) bsel = 4 * tid + 1;
              else bsel = 4 * tid;
            } }
          ibc[0] = bsel;
        }
      }
    }
    __syncthreads();
    if (ibc[0] >= 0) {
      const int Bstar = ibc[0];
      if (tid == 0) *lcnt = 0;
      __syncthreads();
#pragma unroll
      for (int j = 0; j < 16; ++j) {
        float v = getv(j);
        float t = (v - lo) * scale;
        int bin = (int)fminf(fmaxf(t, 0.0f), 255.0f);
        if (bin >= Bstar) {
          int tt = atomicAdd(lcnt, 1);
          if (tt < CAP) { oVal[tt] = v; oIdx[tt] = geti(j); }
        }
      }
      __syncthreads();
      if (tid == 0) *oCnt = min(*lcnt, CAP);
      return;
    }
    range *= 4.0f;
    __syncthreads();
  }
  if (tid == 0) *oCnt = 0;
}

// ---------------- kernel 0: gather prx, build A' = [features; mem[prx]] ----------------
__global__ void prep_kernel(const float* __restrict__ features,
                            const int* __restrict__ targets,
                            const int* __restrict__ all_prx,
                            const float* __restrict__ mem,
                            float* __restrict__ A2,
                            int* __restrict__ prxArr) {
  const int b = blockIdx.x;
  const int k = threadIdx.x;
  const int t = targets[b];
  const int pr = all_prx[t];
  if (k == 0) prxArr[b] = pr;
  A2[b * D_DIM + k] = features[b * D_DIM + k];
  A2[(B_SZ + b) * D_DIM + k] = mem[(size_t)pr * D_DIM + k];
}

// ---------------- kernel 1: split-fp16 3-pass MFMA GEMM ----------------
__global__ __launch_bounds__(256) void gemm_mfma(const float* __restrict__ A,
                                                 const float* __restrict__ Bm,
                                                 float* __restrict__ Co) {
  __shared__ _Float16 Ah[128][32], Al[128][32], Bh[128][32], Bl[128][32];
  const int tid = threadIdx.x;
  const int lane = tid & 63;
  const int wid = tid >> 6;
  const int wr = wid >> 1, wc = wid & 1;
  const int orig = (blockIdx.x & 7) * 128 + (blockIdx.x >> 3);
  const int rowBase = (orig & 3) << 7;
  const int colBase = (orig >> 2) << 7;

  const int trow = tid >> 3;
  const int tseg = tid & 7;

  floatx4 acc[4][4];
#pragma unroll
  for (int i = 0; i < 4; ++i)
#pragma unroll
    for (int j = 0; j < 4; ++j) {
      acc[i][j][0] = 0.f; acc[i][j][1] = 0.f; acc[i][j][2] = 0.f; acc[i][j][3] = 0.f;
    }

  const int fr = lane & 15;
  const int kg = (lane >> 4) << 3;

  for (int step = 0; step < 8; ++step) {
    const int k0 = step << 5;
    float4 sa[4], sb[4];
#pragma unroll
    for (int p = 0; p < 4; ++p) {
      const int r = trow + (p << 5);
      sa[p] = *(const float4*)(A  + (size_t)(rowBase + r) * D_DIM + k0 + tseg * 4);
      sb[p] = *(const float4*)(Bm + (size_t)(colBase + r) * D_DIM + k0 + tseg * 4);
    }
    __syncthreads();
#pragma unroll
    for (int p = 0; p < 4; ++p) {
      const int r = trow + (p << 5);
      float4 v = sa[p];
      half4v h, l;
      h[0] = (_Float16)v.x; l[0] = (_Float16)(v.x - (float)h[0]);
      h[1] = (_Float16)v.y; l[1] = (_Float16)(v.y - (float)h[1]);
      h[2] = (_Float16)v.z; l[2] = (_Float16)(v.z - (float)h[2]);
      h[3] = (_Float16)v.w; l[3] = (_Float16)(v.w - (float)h[3]);
      *(half4v*)&Ah[r][tseg * 4] = h;
      *(half4v*)&Al[r][tseg * 4] = l;
      v = sb[p];
      h[0] = (_Float16)v.x; l[0] = (_Float16)(v.x - (float)h[0]);
      h[1] = (_Float16)v.y; l[1] = (_Float16)(v.y - (float)h[1]);
      h[2] = (_Float16)v.z; l[2] = (_Float16)(v.z - (float)h[2]);
      h[3] = (_Float16)v.w; l[3] = (_Float16)(v.w - (float)h[3]);
      *(half4v*)&Bh[r][tseg * 4] = h;
      *(half4v*)&Bl[r][tseg * 4] = l;
    }
    __syncthreads();
    half8 ah[4], al[4], bh[4], bl[4];
#pragma unroll
    for (int f = 0; f < 4; ++f) {
      ah[f] = *(const half8*)&Ah[wr * 64 + f * 16 + fr][kg];
      al[f] = *(const half8*)&Al[wr * 64 + f * 16 + fr][kg];
      bh[f] = *(const half8*)&Bh[wc * 64 + f * 16 + fr][kg];
      bl[f] = *(const half8*)&Bl[wc * 64 + f * 16 + fr][kg];
    }
#pragma unroll
    for (int fm = 0; fm < 4; ++fm)
#pragma unroll
      for (int fn = 0; fn < 4; ++fn) {
        acc[fm][fn] = __builtin_amdgcn_mfma_f32_16x16x32_f16(ah[fm], bh[fn], acc[fm][fn], 0, 0, 0);
        acc[fm][fn] = __builtin_amdgcn_mfma_f32_16x16x32_f16(ah[fm], bl[fn], acc[fm][fn], 0, 0, 0);
        acc[fm][fn] = __builtin_amdgcn_mfma_f32_16x16x32_f16(al[fm], bh[fn], acc[fm][fn], 0, 0, 0);
      }
  }
  const int rsub = (lane >> 4) << 2;
#pragma unroll
  for (int fm = 0; fm < 4; ++fm)
#pragma unroll
    for (int fn = 0; fn < 4; ++fn) {
      const int r0 = rowBase + wr * 64 + fm * 16 + rsub;
      const int c0 = colBase + wc * 64 + fn * 16 + fr;
#pragma unroll
      for (int r = 0; r < 4; ++r)
        Co[(size_t)(r0 + r) * P_CNT + c0] = acc[fm][fn][r];
    }
}

// ---------------- kernel P1: per-slice partials (2048 blocks) ----------------
__global__ __launch_bounds__(256) void persample1(
    const float* __restrict__ OUT, const int* __restrict__ cams,
    const int* __restrict__ prxArr,
    float* __restrict__ pmaxA, float* __restrict__ imA, float* __restrict__ isA,
    float* __restrict__ camV, int* __restrict__ camI,
    int* __restrict__ cxCnt, float* __restrict__ cxVal, int* __restrict__ cxIdx,
    int* __restrict__ smCnt, float* __restrict__ smVal, int* __restrict__ smIdx) {
  __shared__ __align__(16) int hist[256];
  __shared__ int ibc[2];
  __shared__ int lcnt;
  __shared__ float red4[4];
  __shared__ float mwS[4], swS[4];
  __shared__ float cvW[32]; __shared__ int ciW[32];

  const int blk = blockIdx.x;
  const int b = blk >> 3, s = blk & 7;
  const int tid = threadIdx.x, lane = tid & 63, wid = tid >> 6;
  const int sl = b * NSLICE + s;
  const float* Srow = OUT + (size_t)b * P_CNT + s * SLICE_N;
  const float* Mrow = OUT + (size_t)(B_SZ + b) * P_CNT + s * SLICE_N;
  const int pr = prxArr[b], cam = cams[b];
  const int gbase = s * SLICE_N + 4 * tid;

  float sc[16];
#pragma unroll
  for (int q = 0; q < 4; ++q) {
    float4 f = ((const float4*)Srow)[tid + 256 * q];
    sc[4 * q + 0] = f.x; sc[4 * q + 1] = f.y; sc[4 * q + 2] = f.z; sc[4 * q + 3] = f.w;
  }
  float mx = sc[0];
#pragma unroll
  for (int j = 1; j < 16; ++j) mx = fmaxf(mx, sc[j]);
  const float Mslice = blockMax4(mx, tid, red4);
  if (tid == 0) pmaxA[sl] = Mslice;

  {
    const bool mine = ((tid & 1) == (cam >> 2));
    const int cc = cam & 3;
    float im = NEG_BIG, is = 0.f;
    if (mine) {
#pragma unroll
      for (int q = 0; q < 4; ++q) {
        float v = (cc == 0) ? sc[4 * q] : (cc == 1) ? sc[4 * q + 1]
                : (cc == 2) ? sc[4 * q + 2] : sc[4 * q + 3];
        if (v <= im) is += expf((v - im) * INVT);
        else { is = is * expf((im - v) * INVT) + 1.f; im = v; }
      }
    }
#pragma unroll
    for (int off = 1; off < 64; off <<= 1) {
      float m2 = __shfl_xor(im, off);
      float s2 = __shfl_xor(is, off);
      float Mx = fmaxf(im, m2);
      is = is * expf((im - Mx) * INVT) + s2 * expf((m2 - Mx) * INVT);
      im = Mx;
    }
    if (lane == 0) { mwS[wid] = im; swS[wid] = is; }
    __syncthreads();
    if (tid == 0) {
      float m0 = mwS[0], s0 = swS[0];
      for (int w = 1; w < 4; ++w) {
        float Mx = fmaxf(m0, mwS[w]);
        s0 = s0 * expf((m0 - Mx) * INVT) + swS[w] * expf((mwS[w] - Mx) * INVT);
        m0 = Mx;
      }
      imA[sl] = m0; isA[sl] = s0;
    }
    __syncthreads();
  }

  const int posBase = pr & ~7;
  auto cval = [&](int j) -> float {
    int p = gbase + ((j >> 2) << 10) + (j & 3);
    return ((unsigned)(p - posBase) < 8u) ? NEG_BIG : sc[j];
  };
  auto gidx = [&](int j) -> int { return gbase + ((j >> 2) << 10) + (j & 3); };
  selectCollect(cval, gidx, 53, Mslice, 2.0f, tid, lane, hist, ibc, &lcnt,
                cxVal + (size_t)sl * CAP, cxIdx + (size_t)sl * CAP, cxCnt + sl);

  float sm[16];
#pragma unroll
  for (int q = 0; q < 4; ++q) {
    float4 g = ((const float4*)Mrow)[tid + 256 * q];
    sm[4 * q + 0] = 0.15f * sc[4 * q + 0] + 0.85f * g.x;
    sm[4 * q + 1] = 0.15f * sc[4 * q + 1] + 0.85f * g.y;
    sm[4 * q + 2] = 0.15f * sc[4 * q + 2] + 0.85f * g.z;
    sm[4 * q + 3] = 0.15f * sc[4 * q + 3] + 0.85f * g.w;
  }

  {
    float cm[4]; int cix[4];
#pragma unroll
    for (int c = 0; c < 4; ++c) { cm[c] = NEG_BIG; cix[c] = 0x7fffffff; }
#pragma unroll
    for (int q = 0; q < 4; ++q)
#pragma unroll
      for (int c = 0; c < 4; ++c) {
        float v = sm[4 * q + c];
        int p = gbase + (q << 10) + c;
        if (v > cm[c]) { cm[c] = v; cix[c] = p; }
      }
    const bool odd = (tid & 1);
    float v8[8]; int i8[8];
#pragma unroll
    for (int c = 0; c < 4; ++c) {
      float ov = __shfl_xor(cm[c], 1); int oi = __shfl_xor(cix[c], 1);
      v8[c]     = odd ? ov : cm[c];   i8[c]     = odd ? oi : cix[c];
      v8[c + 4] = odd ? cm[c] : ov;   i8[c + 4] = odd ? cix[c] : oi;
    }
#pragma unroll
    for (int off = 2; off <= 32; off <<= 1)
#pragma unroll
      for (int c = 0; c < 8; ++c) {
        float vv = __shfl_xor(v8[c], off); int ii = __shfl_xor(i8[c], off);
        if (vv > v8[c] || (vv == v8[c] && ii < i8[c])) { v8[c] = vv; i8[c] = ii; }
      }
    if (lane < 8) {
#pragma unroll
      for (int c = 0; c < 8; ++c)
        if (lane == c) { cvW[wid * 8 + c] = v8[c]; ciW[wid * 8 + c] = i8[c]; }
    }
    __syncthreads();
    if (tid < 8) {
      float v = cvW[tid]; int ix = ciW[tid];
      for (int w = 1; w < 4; ++w) {
        float v2 = cvW[w * 8 + tid]; int i2 = ciW[w * 8 + tid];
        if (v2 > v || (v2 == v && i2 < ix)) { v = v2; ix = i2; }
      }
      camV[(size_t)sl * 8 + tid] = v; camI[(size_t)sl * 8 + tid] = ix;
    }
    __syncthreads();
  }

  float mx2 = sm[0];
#pragma unroll
  for (int j = 1; j < 16; ++j) mx2 = fmaxf(mx2, sm[j]);
  const float Ms = blockMax4(mx2, tid, red4);
  auto sval = [&](int j) -> float { return sm[j]; };
  selectCollect(sval, gidx, 56, Ms, 0.35f, tid, lane, hist, ibc, &lcnt,
                smVal + (size_t)sl * CAP, smIdx + (size_t)sl * CAP, smCnt + sl);
}

// ---------------- kernel P2: per-sample merge (256 blocks x 1024 thr, split-task) ----
// Waves 0-7: cross pipeline.  Waves 8-15: online (cam merge + rank + LSE).
__global__ __launch_bounds__(1024) void persample2(
    const float* __restrict__ OUT, const int* __restrict__ prxArr,
    const float* __restrict__ pmaxA, const float* __restrict__ imA,
    const float* __restrict__ isA,
    const float* __restrict__ camV, const int* __restrict__ camI,
    const int* __restrict__ cxCnt, const float* __restrict__ cxVal,
    const int* __restrict__ cxIdx,
    const int* __restrict__ smCnt, const float* __restrict__ smVal,
    const int* __restrict__ smIdx,
    float* __restrict__ intraArr, float* __restrict__ crossArr,
    float* __restrict__ onlArr) {
  __shared__ __align__(16) float vbufC[1040];
  __shared__ __align__(16) int   ibufC[1040];
  __shared__ __align__(16) float vbufS[1040];
  __shared__ __align__(16) int   ibufS[1040];
  __shared__ int   offsC[9], offsS[9];
  __shared__ float MM[1];
  __shared__ int   ch[3];
  __shared__ float sbuf[56];
  __shared__ int   scnt;
  __shared__ float slotE[8];     // cross exp partials per wave
  __shared__ float slotL[1];     // cross pos-linear partial (wave 0)
  __shared__ float imS[8], isS[8];

  const int b = blockIdx.x;
  const int tid = threadIdx.x;
  const int lane = tid & 63;
  const int wv = tid >> 6;                 // 0..15
  const float* Srow = OUT + (size_t)b * P_CNT;
  const int pr = prxArr[b];
  const int posBase = pr & ~7;

  // ================= PHASE 1: all global inputs fetched concurrently =========
  if (tid < 8) {                            // global max (wave 0)
    float v = pmaxA[b * NSLICE + tid];
#pragma unroll
    for (int off = 1; off < 8; off <<= 1) v = fmaxf(v, __shfl_xor(v, off));
    if (tid == 0) MM[0] = v;
  }
  if (tid == 32) {                          // cross offsets
    int4 a = *(const int4*)&cxCnt[b * 8];
    int4 d = *(const int4*)&cxCnt[b * 8 + 4];
    int o = 0;
    offsC[0] = 0; o += a.x; offsC[1] = o; o += a.y; offsC[2] = o;
    o += a.z; offsC[3] = o; o += a.w; offsC[4] = o;
    o += d.x; offsC[5] = o; o += d.y; offsC[6] = o;
    o += d.z; offsC[7] = o; o += d.w; offsC[8] = o;
  }
  if (tid == 34) {                          // sims offsets
    int4 a = *(const int4*)&smCnt[b * 8];
    int4 d = *(const int4*)&smCnt[b * 8 + 4];
    int o = 0;
    offsS[0] = 0; o += a.x; offsS[1] = o; o += a.y; offsS[2] = o;
    o += a.z; offsS[3] = o; o += a.w; offsS[4] = o;
    o += d.x; offsS[5] = o; o += d.y; offsS[6] = o;
    o += d.z; offsS[7] = o; o += d.w; offsS[8] = o;
  }
  if (tid >= 64 && tid < 72) imS[tid - 64] = imA[b * NSLICE + (tid - 64)];
  if (tid >= 72 && tid < 80) isS[tid - 72] = isA[b * NSLICE + (tid - 72)];
  if (tid == 96) scnt = 0;
  if (wv == 8) {                            // cam merge + top-3 (one wave)
    const int s = lane >> 3, c = lane & 7;
    float v = camV[(size_t)(b * NSLICE + s) * 8 + c];
    int  ix = camI[(size_t)(b * NSLICE + s) * 8 + c];
#pragma unroll
    for (int off = 8; off <= 32; off <<= 1) {
      float v2 = __shfl_xor(v, off);
      int   i2 = __shfl_xor(ix, off);
      if (v2 > v || (v2 == v && i2 < ix)) { v = v2; ix = i2; }
    }
    // lanes 0..7 hold per-cam best; all lanes run the gather loop
    unsigned used = 0;
    for (int k = 0; k < 3; ++k) {
      float best = NEG_BIG; int bc = 0;
      for (int c2 = 0; c2 < 8; ++c2) {
        float vv = __shfl(v, c2); int ii = __shfl(ix, c2);
        if (!((used >> c2) & 1u) && vv > best) { best = vv; bc = c2; (void)ii; }
      }
      used |= 1u << bc;
      int chosen = __shfl(ix, bc);
      if (lane == 0) ch[k] = chosen;
    }
  }
  __syncthreads();

  // ================= PHASE 2: staging (one wave per slice, both groups) ======
  const int C = offsC[8];
  const int Cp = (C + 3) & ~3;
  const int C2 = offsS[8];
  const int C2p = (C2 + 3) & ~3;
  const int c0 = ch[0], c1 = ch[1], c2 = ch[2];

  if (wv < 8) {                             // cross: wave wv stages slice wv
    const int o = offsC[wv], n = offsC[wv + 1] - o;
    const size_t base = (size_t)(b * NSLICE + wv) * CAP;
    for (int i = lane; i < n; i += 64) {
      vbufC[o + i] = cxVal[base + i];
      ibufC[o + i] = cxIdx[base + i];
    }
  } else {                                  // online: wave wv-8 stages slice wv-8
    const int w = wv - 8;
    const int o = offsS[w], n = offsS[w + 1] - o;
    const size_t base = (size_t)(b * NSLICE + w) * CAP;
    for (int i = lane; i < n; i += 64) {
      float v = smVal[base + i];
      int  ix = smIdx[base + i];
      if (ix == c0 || ix == c1 || ix == c2) v = NEG_BIG;
      vbufS[o + i] = v; ibufS[o + i] = ix;
    }
  }
  if (tid >= 40 && tid < 44) {              // sentinel pads
    int i = C + (tid - 40);
    if (i < Cp) { vbufC[i] = NEG_BIG; ibufC[i] = 0x7fffffff; }
  }
  if (tid >= 44 && tid < 48) {
    int i = C2 + (tid - 44);
    if (i < C2p) { vbufS[i] = NEG_BIG; ibufS[i] = 0x7fffffff; }
  }
  float pv = 0.f;
  if (tid < 8) pv = Srow[posBase + tid];    // pos scores (wave 0, registers)
  if (tid == 80) {                          // intra finalize (independent)
    float m0 = imS[0], s0 = isS[0];
    for (int w = 1; w < NSLICE; ++w) {
      float Mx = fmaxf(m0, imS[w]);
      s0 = s0 * expf((m0 - Mx) * INVT) + isS[w] * expf((imS[w] - Mx) * INVT);
      m0 = Mx;
    }
    intraArr[b] = -((Srow[pr] - m0) * INVT - logf(s0));
  }
  __syncthreads();

  // ================= PHASE 3: rank sweeps (groups in parallel) ===============
  const float M = MM[0];
  if (wv < 8) {
    // cross: 512 threads, 2 candidates each
    const int gtid = tid;                   // 0..511
    float ve0 = (gtid < C) ? vbufC[gtid] : NEG_BIG;
    int   ie0 = (gtid < C) ? ibufC[gtid] : 0x7fffffff;
    float ve1 = (gtid + 512 < C) ? vbufC[gtid + 512] : NEG_BIG;
    int   ie1 = (gtid + 512 < C) ? ibufC[gtid + 512] : 0x7fffffff;
    int rk0 = 0, rk1 = 0;
    const float4* v4 = (const float4*)vbufC;
    const int4*   q4 = (const int4*)ibufC;
    for (int m4 = 0; m4 < (Cp >> 2); ++m4) {
      float4 vm = v4[m4]; int4 im = q4[m4];
      rk0 += (vm.x > ve0) || (vm.x == ve0 && im.x < ie0);
      rk0 += (vm.y > ve0) || (vm.y == ve0 && im.y < ie0);
      rk0 += (vm.z > ve0) || (vm.z == ve0 && im.z < ie0);
      rk0 += (vm.w > ve0) || (vm.w == ve0 && im.w < ie0);
      rk1 += (vm.x > ve1) || (vm.x == ve1 && im.x < ie1);
      rk1 += (vm.y > ve1) || (vm.y == ve1 && im.y < ie1);
      rk1 += (vm.z > ve1) || (vm.z == ve1 && im.z < ie1);
      rk1 += (vm.w > ve1) || (vm.w == ve1 && im.w < ie1);
    }
    float myexp = 0.f;
    if (gtid < C && rk0 < 50) myexp += expf((ve0 - M) * INVT);
    if (gtid + 512 < C && rk1 < 50) myexp += expf((ve1 - M) * INVT);
    float pl = 0.f;
    if (tid < 8) { myexp += expf((pv - M) * INVT); pl = (pv - M) * INVT; }
#pragma unroll
    for (int off = 1; off < 64; off <<= 1) { myexp += __shfl_xor(myexp, off); pl += __shfl_xor(pl, off); }
    if (lane == 0) slotE[wv] = myexp;
    if (tid == 0) slotL[0] = pl;
  } else {
    // online: 512 threads, 2 candidates each
    const int gtid = tid - 512;             // 0..511
    float ve0 = (gtid < C2) ? vbufS[gtid] : NEG_BIG;
    int   ie0 = (gtid < C2) ? ibufS[gtid] : 0x7fffffff;
    float ve1 = (gtid + 512 < C2) ? vbufS[gtid + 512] : NEG_BIG;
    int   ie1 = (gtid + 512 < C2) ? ibufS[gtid + 512] : 0x7fffffff;
    int rk0 = 0, rk1 = 0;
    const float4* v4 = (const float4*)vbufS;
    const int4*   q4 = (const int4*)ibufS;
    for (int m4 = 0; m4 < (C2p >> 2); ++m4) {
      float4 vm = v4[m4]; int4 im = q4[m4];
      rk0 += (vm.x > ve0) || (vm.x == ve0 && im.x < ie0);
      rk0 += (vm.y > ve0) || (vm.y == ve0 && im.y < ie0);
      rk0 += (vm.z > ve0) || (vm.z == ve0 && im.z < ie0);
      rk0 += (vm.w > ve0) || (vm.w == ve0 && im.w < ie0);
      rk1 += (vm.x > ve1) || (vm.x == ve1 && im.x < ie1);
      rk1 += (vm.y > ve1) || (vm.y == ve1 && im.y < ie1);
      rk1 += (vm.z > ve1) || (vm.z == ve1 && im.z < ie1);
      rk1 += (vm.w > ve1) || (vm.w == ve1 && im.w < ie1);
    }
    if (gtid < C2 && ve0 > -1.0e38f && rk0 < 50) {
      int t = atomicAdd(&scnt, 1);
      if (t < 50) sbuf[t] = Srow[ie0];
    }
    if (gtid + 512 < C2 && ve1 > -1.0e38f && rk1 < 50) {
      int t = atomicAdd(&scnt, 1);
      if (t < 50) sbuf[t] = Srow[ie1];
    }
    if (wv == 8 && lane < 3) sbuf[50 + lane] = Srow[ch[lane]];
  }
  __syncthreads();

  // ================= PHASE 4: finals =========================================
  if (tid == 0) {
    float stot = 0.f;
#pragma unroll
    for (int w = 0; w < 8; ++w) stot += slotE[w];
    float lse = logf(stot);
    crossArr[b] = -(slotL[0] - 8.f * lse) * 0.125f;
  }
  if (wv == 8) {
    float v = (lane < 53) ? sbuf[lane] : NEG_BIG;
    float mm = v;
#pragma unroll
    for (int off = 1; off < 64; off <<= 1) mm = fmaxf(mm, __shfl_xor(mm, off));
    float e = (lane < 53) ? expf((v - mm) * INVT) : 0.f;
    float ss = e;
#pragma unroll
    for (int off = 1; off < 64; off <<= 1) ss += __shfl_xor(ss, off);
    float lse = logf(ss);
    float c = (lane >= 50 && lane < 53) ? ((v - mm) * INVT - lse) : 0.f;
#pragma unroll
    for (int off = 1; off < 64; off <<= 1) c += __shfl_xor(c, off);
    if (lane == 0) onlArr[b] = -c * (1.0f / 3.0f);
  }
}

// ---------------- kernel 3: per-camera means -> scalar ----------------
__global__ void finalize(const int* __restrict__ cams,
                         const float* __restrict__ ia,
                         const float* __restrict__ ca,
                         const float* __restrict__ oa,
                         float* __restrict__ out) {
  if (blockIdx.x == 0 && threadIdx.x == 0) {
    float s[8] = {}; float n[8] = {};
    for (int b = 0; b < B_SZ; ++b) {
      int c = cams[b];
      s[c] += ia[b] + ca[b] + oa[b];
      n[c] += 1.f;
    }
    float tot = 0.f;
    for (int c = 0; c < 8; ++c)
      if (n[c] > 0.f) tot += s[c] / n[c];
    out[0] = tot;
  }
}

extern "C" void kernel_launch(void* const* d_in, const int* in_sizes, int n_in,
                              void* d_out, int out_size, void* d_ws, size_t ws_size,
                              hipStream_t stream) {
  const float* features = (const float*)d_in[0];
  const int*   targets  = (const int*)d_in[1];
  const int*   cams     = (const int*)d_in[2];
  const float* mem      = (const float*)d_in[4];
  const int*   all_prx  = (const int*)d_in[6];

  float* ws = (float*)d_ws;
  float* A2  = ws;                               // 512*256
  float* OUT = ws + 512 * D_DIM;                 // 512*32768
  char*  tail = (char*)(OUT + (size_t)512 * P_CNT);

  int*   prxArr  = (int*)tail;                  tail += B_SZ * 4;
  float* intraArr = (float*)tail;               tail += B_SZ * 4;
  float* crossArr = (float*)tail;               tail += B_SZ * 4;
  float* onlArr   = (float*)tail;               tail += B_SZ * 4;
  float* pmaxA = (float*)tail;                  tail += B_SZ * NSLICE * 4;
  float* imA   = (float*)tail;                  tail += B_SZ * NSLICE * 4;
  float* isA   = (float*)tail;                  tail += B_SZ * NSLICE * 4;
  float* camV  = (float*)tail;                  tail += B_SZ * NSLICE * 8 * 4;
  int*   camI  = (int*)tail;                    tail += B_SZ * NSLICE * 8 * 4;
  int*   cxCnt = (int*)tail;                    tail += B_SZ * NSLICE * 4;
  int*   smCnt = (int*)tail;                    tail += B_SZ * NSLICE * 4;
  float* cxVal = (float*)tail;                  tail += (size_t)B_SZ * NSLICE * CAP * 4;
  int*   cxIdx = (int*)tail;                    tail += (size_t)B_SZ * NSLICE * CAP * 4;
  float* smVal = (float*)tail;                  tail += (size_t)B_SZ * NSLICE * CAP * 4;
  int*   smIdx = (int*)tail;                    tail += (size_t)B_SZ * NSLICE * CAP * 4;

  prep_kernel<<<B_SZ, D_DIM, 0, stream>>>(features, targets, all_prx, mem, A2, prxArr);
  gemm_mfma<<<1024, 256, 0, stream>>>(A2, mem, OUT);
  persample1<<<B_SZ * NSLICE, 256, 0, stream>>>(OUT, cams, prxArr,
      pmaxA, imA, isA, camV, camI, cxCnt, cxVal, cxIdx, smCnt, smVal, smIdx);
  persample2<<<B_SZ, 1024, 0, stream>>>(OUT, prxArr,
      pmaxA, imA, isA, camV, camI, cxCnt, cxVal, cxIdx, smCnt, smVal, smIdx,
      intraArr, crossArr, onlArr);
  finalize<<<1, 64, 0, stream>>>(cams, intraArr, crossArr, onlArr, (float*)d_out);
}